// Round 15
// baseline (368.660 us; speedup 1.0000x reference)
//
#include <hip/hip_runtime.h>
#include <hip/hip_bf16.h>

typedef unsigned short u16;
typedef __attribute__((ext_vector_type(4))) float f32x4;
typedef __attribute__((ext_vector_type(8))) short short8;

// B=8 QLEN=256 D=1024 H=16 HD=64 FFN=4096 PAGE=16 KV_TOTAL=4096 P=256
// PREFIX=3840 SCALE=0.125
#define MODE_QKV 0
#define MODE_WO  1
#define MODE_F1  2
#define MODE_F2  3

__device__ inline u16 f2bf(float f) {
    __hip_bfloat16 h = __float2bfloat16(f);
    return *(u16*)&h;
}
__device__ inline float bf2f(u16 u) {
    union { unsigned int i; float f; } x; x.i = ((unsigned int)u) << 16; return x.f;
}

typedef __attribute__((address_space(3))) unsigned int lds_u32_t;
typedef const __attribute__((address_space(1))) unsigned int glb_u32_t;
__device__ inline void gload16(const u16* g, u16* l) {
    __builtin_amdgcn_global_load_lds((glb_u32_t*)(const void*)g,
                                     (lds_u32_t*)(void*)l, 16, 0, 0);
}

// ---------------- prep: Wq/Wk/Wv transposes + x cast ----------------
__global__ __launch_bounds__(256) void prep_wx(
    const float* __restrict__ Wq, const float* __restrict__ Wk,
    const float* __restrict__ Wv, const float* __restrict__ x,
    u16* __restrict__ WqkvT, u16* __restrict__ xb) {
    int bid = blockIdx.x;
    int tid = threadIdx.x;
    int tx = tid & 31, ty = tid >> 5;
    if (bid >= 3072) {
        int i = (bid - 3072) * 256 + tid;
        const float4* p = (const float4*)(x + (size_t)i * 8);
        float4 a = p[0], b = p[1];
        u16 t[8] = {f2bf(a.x), f2bf(a.y), f2bf(a.z), f2bf(a.w),
                    f2bf(b.x), f2bf(b.y), f2bf(b.z), f2bf(b.w)};
        *(uint4*)(xb + (size_t)i * 8) = *(const uint4*)t;
        return;
    }
    int m = bid >> 10, r = bid & 1023;
    const float* src = (m == 0) ? Wq : (m == 1) ? Wk : Wv;
    u16* dst = WqkvT + (size_t)m * 1024 * 1024;
    __shared__ float t[32][33];
    int n0 = (r & 31) * 32, k0 = (r >> 5) * 32;
#pragma unroll
    for (int j = 0; j < 32; j += 8)
        t[ty + j][tx] = src[(size_t)(k0 + ty + j) * 1024 + n0 + tx];
    __syncthreads();
#pragma unroll
    for (int j = 0; j < 32; j += 8)
        dst[(size_t)(n0 + ty + j) * 1024 + k0 + tx] = f2bf(t[tx][ty + j]);
}

// ---------------- LN after WO: t = p0+p1+bo+resid; LN -> xln1f, xln1b ------------
__global__ __launch_bounds__(256) void ln_wo(const float* __restrict__ p0,
                                             const float* __restrict__ p1,
                                             const float* __restrict__ bo,
                                             const float* __restrict__ resid,
                                             const float* __restrict__ g,
                                             const float* __restrict__ be,
                                             float* __restrict__ outf,
                                             u16* __restrict__ outb) {
    int row = blockIdx.x;
    int tid = threadIdx.x;
    int c = tid * 4;
    size_t o = (size_t)row * 1024 + c;
    f32x4 v = *(const f32x4*)(p0 + o) + *(const f32x4*)(p1 + o)
            + *(const f32x4*)(bo + c) + *(const f32x4*)(resid + o);
    float s = v[0] + v[1] + v[2] + v[3];
#pragma unroll
    for (int m = 1; m < 64; m <<= 1) s += __shfl_xor(s, m, 64);
    __shared__ float red1[4], red2[4];
    int w = tid >> 6;
    if ((tid & 63) == 0) red1[w] = s;
    __syncthreads();
    float mu = (red1[0] + red1[1] + red1[2] + red1[3]) * (1.0f / 1024.0f);
    f32x4 d = v - mu;
    float q = d[0] * d[0] + d[1] * d[1] + d[2] * d[2] + d[3] * d[3];
#pragma unroll
    for (int m = 1; m < 64; m <<= 1) q += __shfl_xor(q, m, 64);
    if ((tid & 63) == 0) red2[w] = q;
    __syncthreads();
    float var = (red2[0] + red2[1] + red2[2] + red2[3]) * (1.0f / 1024.0f);
    float rs = rsqrtf(var + 1e-5f);
    f32x4 gg = *(const f32x4*)(g + c), bb = *(const f32x4*)(be + c);
    f32x4 ov = d * rs * gg + bb;
    *(f32x4*)(outf + o) = ov;
    u16 t[4] = {f2bf(ov[0]), f2bf(ov[1]), f2bf(ov[2]), f2bf(ov[3])};
    *(uint2*)&outb[o] = *(const uint2*)t;
}

// ------- final LN: lr = q0+q1+q2+q3+b2 -> out_lr; LN(lr + xln1f) -> out_x --------
__global__ __launch_bounds__(256) void ln_f2(const float* __restrict__ q0,
                                             const float* __restrict__ b2,
                                             const float* __restrict__ xln1f,
                                             const float* __restrict__ g,
                                             const float* __restrict__ be,
                                             float* __restrict__ out_lr,
                                             float* __restrict__ out_x) {
    int row = blockIdx.x;
    int tid = threadIdx.x;
    int c = tid * 4;
    size_t o = (size_t)row * 1024 + c;
    const size_t st = (size_t)2048 * 1024;
    f32x4 v = *(const f32x4*)(q0 + o) + *(const f32x4*)(q0 + st + o)
            + *(const f32x4*)(q0 + 2 * st + o) + *(const f32x4*)(q0 + 3 * st + o)
            + *(const f32x4*)(b2 + c);
    *(f32x4*)(out_lr + o) = v;
    v = v + *(const f32x4*)(xln1f + o);
    float s = v[0] + v[1] + v[2] + v[3];
#pragma unroll
    for (int m = 1; m < 64; m <<= 1) s += __shfl_xor(s, m, 64);
    __shared__ float red1[4], red2[4];
    int w = tid >> 6;
    if ((tid & 63) == 0) red1[w] = s;
    __syncthreads();
    float mu = (red1[0] + red1[1] + red1[2] + red1[3]) * (1.0f / 1024.0f);
    f32x4 d = v - mu;
    float q = d[0] * d[0] + d[1] * d[1] + d[2] * d[2] + d[3] * d[3];
#pragma unroll
    for (int m = 1; m < 64; m <<= 1) q += __shfl_xor(q, m, 64);
    if ((tid & 63) == 0) red2[w] = q;
    __syncthreads();
    float var = (red2[0] + red2[1] + red2[2] + red2[3]) * (1.0f / 1024.0f);
    float rs = rsqrtf(var + 1e-5f);
    f32x4 gg = *(const f32x4*)(g + c), bb = *(const f32x4*)(be + c);
    *(f32x4*)(out_x + o) = d * rs * gg + bb;
}

// ---------------- GEMM body: tile 128x128, BK=64, row stride lda ----------------
template <int MODE>
__device__ __forceinline__ void gemm_body(
    u16* As, u16* Bs, int m0, int n0,
    const u16* __restrict__ A, const u16* __restrict__ Bt, int lda, int Kspan, int N,
    const float* __restrict__ bias0, const float* __restrict__ bias1,
    const float* __restrict__ bias2,
    float* __restrict__ o0, u16* __restrict__ ob,
    u16* __restrict__ kbf, u16* __restrict__ vbf, const int* __restrict__ kvidx) {
    int tid = threadIdx.x;
    int l = tid & 63, w = tid >> 6;
    int wr = w >> 1, wc = w & 1;
    int lr = l & 15, lg = l >> 4;
    int lrow8 = l >> 3;
    int scol = ((l & 7) ^ lrow8) << 3;
    f32x4 acc[4][4] = {};
    for (int kb = 0; kb < Kspan; kb += 64) {
#pragma unroll
        for (int p = 0; p < 4; ++p) {
            int chunk = p * 4 + w;
            int r = chunk * 8 + lrow8;
            gload16(&A[(size_t)(m0 + r) * lda + kb + scol], &As[chunk * 512]);
            gload16(&Bt[(size_t)(n0 + r) * lda + kb + scol], &Bs[chunk * 512]);
        }
        __syncthreads();
#pragma unroll
        for (int kk = 0; kk < 2; ++kk) {
            short8 a[4], b[4];
            int c0 = kk * 32 + lg * 8;
#pragma unroll
            for (int mi = 0; mi < 4; mi++) {
                int row = wr * 64 + mi * 16 + lr;
                a[mi] = *(const short8*)&As[row * 64 + (c0 ^ ((row & 7) << 3))];
            }
#pragma unroll
            for (int ni = 0; ni < 4; ni++) {
                int row = wc * 64 + ni * 16 + lr;
                b[ni] = *(const short8*)&Bs[row * 64 + (c0 ^ ((row & 7) << 3))];
            }
#pragma unroll
            for (int mi = 0; mi < 4; mi++)
#pragma unroll
                for (int ni = 0; ni < 4; ni++)
                    acc[mi][ni] = __builtin_amdgcn_mfma_f32_16x16x32_bf16(
                        a[mi], b[ni], acc[mi][ni], 0, 0, 0);
        }
        __syncthreads();
    }
#pragma unroll
    for (int mi = 0; mi < 4; mi++) {
#pragma unroll
        for (int ni = 0; ni < 4; ni++) {
#pragma unroll
            for (int r = 0; r < 4; r++) {
                int row = m0 + wr * 64 + mi * 16 + lg * 4 + r;
                int col = n0 + wc * 64 + ni * 16 + lr;
                float v = acc[mi][ni][r];
                if constexpr (MODE == MODE_QKV) {
                    int sel = col >> 10, c = col & 1023;
                    int b = row >> 8, ii = row & 255;
                    int h = (c >> 6), hd = c & 63;
                    if (sel == 0) {
                        ob[(size_t)row * 1024 + c] = f2bf((v + bias0[c]) * 0.125f);
                    } else if (sel == 1) {
                        float val = v + bias1[c];
                        int page = kvidx[b * 256 + 240 + (ii >> 4)];
                        o0[(size_t)page * 32768 + (size_t)(ii & 15) * 1024 + c] = val;
                        kbf[((size_t)(b * 16 + h) * 4096 + 3840 + ii) * 64 + hd] = f2bf(val);
                    } else {
                        float val = v + bias2[c];
                        int page = kvidx[b * 256 + 240 + (ii >> 4)];
                        o0[(size_t)page * 32768 + 16384 + (size_t)(ii & 15) * 1024 + c] = val;
                        vbf[((size_t)(b * 16 + h) * 64 + hd) * 4096 + 3840 + ii] = f2bf(val);
                    }
                } else if constexpr (MODE == MODE_F1) {
                    float t = v + bias0[col];
                    ob[(size_t)row * N + col] = f2bf(fmaxf(t, 0.0f));
                } else { // raw split-K partial
                    o0[(size_t)row * N + col] = v;
                }
            }
        }
    }
}

// split-K wrapper
template <int MODE>
__global__ __launch_bounds__(256) void gemm_nt(
    const u16* __restrict__ A, const u16* __restrict__ Bt,
    int lda, int Kspan, int N, int gx, int nper,
    const float* __restrict__ bias0,
    float* __restrict__ o0, u16* __restrict__ ob, size_t osplit) {
    __shared__ __align__(16) u16 smem[128 * 64 * 2];
    int bid = blockIdx.x;
    int split = bid / nper, t = bid % nper;
    gemm_body<MODE>(smem, smem + 128 * 64, (t / gx) * 128, (t % gx) * 128,
                    A + (size_t)split * Kspan, Bt + (size_t)split * Kspan,
                    lda, Kspan, N, bias0, nullptr, nullptr,
                    o0 ? o0 + (size_t)split * osplit : nullptr, ob,
                    nullptr, nullptr, nullptr);
}

// ---- WO with fused attn-combine: A staged from bf16 pOct partials + pL norm ----
// grid 256: split = bid>>7 (K half), t = bid&127: m0=(t>>3)*128, n0=(t&7)*128
__global__ __launch_bounds__(256) void gemm_wo(
    const u16* __restrict__ pOct, const float* __restrict__ pL,
    const u16* __restrict__ Bt, float* __restrict__ p0) {
    __shared__ __align__(16) u16 As[128 * 64];
    __shared__ __align__(16) u16 Bs[128 * 64];
    int bid = blockIdx.x;
    int split = bid >> 7, t = bid & 127;
    int m0 = (t >> 3) * 128, n0 = (t & 7) * 128;
    int tid = threadIdx.x;
    int l = tid & 63, w = tid >> 6;
    int wr = w >> 1, wc = w & 1;
    int lr = l & 15, lg = l >> 4;
    int lrow8 = l >> 3;
    int scol = ((l & 7) ^ lrow8) << 3;
    int acol = (l & 7) << 3;
    int bb = m0 >> 8, q0 = m0 & 255;
    f32x4 acc[4][4] = {};
    for (int kb = 0; kb < 512; kb += 64) {
        int k0 = split * 512 + kb;
        int h = k0 >> 6;
#pragma unroll
        for (int p = 0; p < 4; ++p) {
            int chunk = p * 4 + w;
            int r = chunk * 8 + lrow8;
            size_t rowbase = ((size_t)bb * 16 + h) * 256 + q0 + r;
            gload16(&Bt[(size_t)(n0 + r) * 1024 + k0 + scol], &Bs[chunk * 512]);
            float ls = pL[rowbase] + pL[32768 + rowbase]
                     + pL[2 * 32768 + rowbase] + pL[3 * 32768 + rowbase];
            float inv = 1.0f / ls;
            float sums[8] = {};
#pragma unroll
            for (int sp = 0; sp < 4; ++sp) {
                u16 a8[8];
                *(uint4*)a8 = *(const uint4*)&pOct[((size_t)sp * 32768 + rowbase) * 64 + acol];
#pragma unroll
                for (int j = 0; j < 8; ++j) sums[j] += bf2f(a8[j]);
            }
            u16 o8[8];
#pragma unroll
            for (int j = 0; j < 8; ++j) o8[j] = f2bf(sums[j] * inv);
            *(uint4*)&As[(size_t)r * 64 + (acol ^ ((r & 7) << 3))] = *(const uint4*)o8;
        }
        __syncthreads();
#pragma unroll
        for (int kk = 0; kk < 2; ++kk) {
            short8 a[4], b[4];
            int c0 = kk * 32 + lg * 8;
#pragma unroll
            for (int mi = 0; mi < 4; mi++) {
                int row = wr * 64 + mi * 16 + lr;
                a[mi] = *(const short8*)&As[row * 64 + (c0 ^ ((row & 7) << 3))];
            }
#pragma unroll
            for (int ni = 0; ni < 4; ni++) {
                int row = wc * 64 + ni * 16 + lr;
                b[ni] = *(const short8*)&Bs[row * 64 + (c0 ^ ((row & 7) << 3))];
            }
#pragma unroll
            for (int mi = 0; mi < 4; mi++)
#pragma unroll
                for (int ni = 0; ni < 4; ni++)
                    acc[mi][ni] = __builtin_amdgcn_mfma_f32_16x16x32_bf16(
                        a[mi], b[ni], acc[mi][ni], 0, 0, 0);
        }
        __syncthreads();
    }
    float* o0 = p0 + (size_t)split * 2048 * 1024;
#pragma unroll
    for (int mi = 0; mi < 4; mi++)
#pragma unroll
        for (int ni = 0; ni < 4; ni++)
#pragma unroll
            for (int r = 0; r < 4; r++) {
                int row = m0 + wr * 64 + mi * 16 + lg * 4 + r;
                int col = n0 + wc * 64 + ni * 16 + lr;
                o0[(size_t)row * 1024 + col] = acc[mi][ni][r];
            }
}

// ---- mega v4: 8064 blocks. bid%21==20 -> QKV GEMM (384); else single-read prefix ----
__global__ __launch_bounds__(256) void mega_prep(
    const u16* __restrict__ xb, const u16* __restrict__ WqkvT,
    const float* __restrict__ bq, const float* __restrict__ bk,
    const float* __restrict__ bv,
    float* __restrict__ out_pt, u16* __restrict__ qbuf,
    u16* __restrict__ Kbf, u16* __restrict__ Vtbf,
    const float* __restrict__ pgt, const int* __restrict__ kvidx) {
    __shared__ __align__(16) u16 smem[128 * 64 * 2];
    int bid = blockIdx.x;
    int tid = threadIdx.x;
    if (bid % 21 == 20) {
        int t = bid / 21;
        gemm_body<MODE_QKV>(smem, smem + 8192, (t / 24) * 128, (t % 24) * 128,
                            xb, WqkvT, 1024, 1024, 3072, bq, bk, bv,
                            out_pt, qbuf, Kbf, Vtbf, kvidx);
        return;
    }
    int idx = (bid / 21) * 20 + (bid % 21);   // 0..7679
    int tile = idx % 60, rest = idx / 60;
    int h = rest & 15, b = rest >> 4;
    int T0 = tile * 64;
    int rr = tid >> 4;
    int hdq = tid & 15;
    u16* vt = smem;      // [64][68]
    size_t kdst_base = ((size_t)(b * 16 + h) * 4096 + T0) * 64;
#pragma unroll
    for (int p = 0; p < 4; ++p) {
        int i = p * 16 + rr;
        int page = kvidx[b * 256 + (T0 >> 4) + p];
        size_t src = (size_t)page * 32768 + (size_t)rr * 1024 + h * 64 + hdq * 4;
        float4 kf = *(const float4*)(pgt + src);
        *(float4*)(out_pt + src) = kf;
        u16 kb4[4] = {f2bf(kf.x), f2bf(kf.y), f2bf(kf.z), f2bf(kf.w)};
        *(uint2*)&Kbf[kdst_base + (size_t)i * 64 + hdq * 4] = *(const uint2*)kb4;
        float4 vf = *(const float4*)(pgt + src + 16384);
        *(float4*)(out_pt + src + 16384) = vf;
        u16 vb4[4] = {f2bf(vf.x), f2bf(vf.y), f2bf(vf.z), f2bf(vf.w)};
        *(uint2*)&vt[i * 68 + hdq * 4] = *(const uint2*)vb4;
    }
    __syncthreads();
    size_t vdst_base = (size_t)(b * 16 + h) * 64 * 4096 + T0;
#pragma unroll
    for (int p = 0; p < 4; ++p) {
        int hd = p * 16 + rr;
        u16 o[4];
#pragma unroll
        for (int j = 0; j < 4; ++j) o[j] = vt[(hdq * 4 + j) * 68 + hd];
        *(uint2*)&Vtbf[vdst_base + (size_t)hd * 4096 + hdq * 4] = *(const uint2*)o;
    }
}

// ---- attention (1024 blocks, XCD-grouped) + Wo/W1/W2 transposes (4608 x 2) ----
__global__ __launch_bounds__(512) void attn_kernel(const u16* __restrict__ qb,
                                                   const u16* __restrict__ Kbf,
                                                   const u16* __restrict__ Vtbf,
                                                   u16* __restrict__ pOct,
                                                   float* __restrict__ pL,
                                                   const float* __restrict__ Wo,
                                                   const float* __restrict__ W1,
                                                   const float* __restrict__ W2,
                                                   u16* __restrict__ WoT,
                                                   u16* __restrict__ W1T,
                                                   u16* __restrict__ W2T) {
    __shared__ u16 Ks[64 * 64];
    __shared__ u16 Vt[64 * 64];
    __shared__ u16 Ps[8][16 * 64];
    int bid = blockIdx.x;
    int tid = threadIdx.x;
    if (bid >= 1024) {
        int sub = tid >> 8, t2 = tid & 255;
        int wb = (bid - 1024) * 2 + sub;   // 0..9215
        const float* src; u16* dst; int K, N, bx, by;
        if (wb < 1024) {
            bx = wb & 31; by = wb >> 5; K = 1024; N = 1024; src = Wo; dst = WoT;
        } else if (wb < 5120) {
            int r = wb - 1024; bx = r & 127; by = r >> 7; K = 1024; N = 4096; src = W1; dst = W1T;
        } else {
            int r = wb - 5120; bx = r & 31; by = r >> 5; K = 4096; N = 1024; src = W2; dst = W2T;
        }
        float* t = sub ? (float*)Vt : (float*)Ks;
        int tx = t2 & 31, ty = t2 >> 5;
        int n0 = bx * 32, k0 = by * 32;
#pragma unroll
        for (int jj = 0; jj < 32; jj += 8)
            t[(ty + jj) * 33 + tx] = src[(size_t)(k0 + ty + jj) * N + n0 + tx];
        __syncthreads();
#pragma unroll
        for (int jj = 0; jj < 32; jj += 8)
            dst[(size_t)(n0 + ty + jj) * K + k0 + tx] = f2bf(t[tx * 33 + ty + jj]);
        return;
    }
    // XCD-locality remap: all 8 (qt,split) blocks of a (b,h) share bid&7 -> same XCD L2
    int xg = bid & 7, tt = bid >> 3;
    int j = tt & 7, ghi = tt >> 3;
    int g = (ghi << 3) | xg;           // 0..127 = b*16+h
    int b = g >> 4, h = g & 15;
    int qt = j >> 2, split = j & 3;
    int l = tid & 63, w = tid >> 6;
    int lr = l & 15, lg = l >> 4;

    int qrow = qt * 128 + w * 16 + lr;
    const u16* qptr = qb + (size_t)(b * 256 + qrow) * 1024 + h * 64 + lg * 8;
    short8 qf0 = *(const short8*)qptr;
    short8 qf1 = *(const short8*)(qptr + 32);

    const u16* kslab = Kbf + (size_t)(b * 16 + h) * 4096 * 64;
    const u16* vslab = Vtbf + (size_t)(b * 16 + h) * 64 * 4096;

    f32x4 octx[4] = {};
    f32x4 lacc = {};
    short8 ones;
#pragma unroll
    for (int jj = 0; jj < 8; jj++) ones[jj] = (short)0x3F80;

    int qbase = 3840 + qt * 128;
    int ntiles = (qbase + 128) >> 6;
    int tstart = split * 16;
    int tend = min(tstart + 16, ntiles);
    int kt0 = tstart * 64, kt1 = tend * 64;

    int srow = tid >> 3, scol8 = (tid & 7) * 8;
    int sdst = srow * 64 + (scol8 ^ ((srow & 7) << 3));
    const u16* kp = kslab + srow * 64 + scol8;
    const u16* vp = vslab + (size_t)srow * 4096 + scol8;

    uint4 kreg = *(const uint4*)(kp + (size_t)kt0 * 64);
    uint4 vreg = *(const uint4*)(vp + kt0);
    for (int kt = kt0; kt < kt1; kt += 64) {
        *(uint4*)&Ks[sdst] = kreg;
        *(uint4*)&Vt[sdst] = vreg;
        __syncthreads();
        bool hn = (kt + 64) < kt1;
        if (hn) {
            kreg = *(const uint4*)(kp + (size_t)(kt + 64) * 64);
            vreg = *(const uint4*)(vp + kt + 64);
        }
        float P[4][4];
        bool need_mask = (kt + 63 > qbase);
        __builtin_amdgcn_s_setprio(1);
#pragma unroll
        for (int ni = 0; ni < 4; ni++) {
            f32x4 s = {};
            int krow = ni * 16 + lr;
            int swz = (krow & 7) << 3;
            short8 k0 = *(const short8*)&Ks[krow * 64 + ((lg * 8) ^ swz)];
            short8 k1 = *(const short8*)&Ks[krow * 64 + ((32 + lg * 8) ^ swz)];
            s = __builtin_amdgcn_mfma_f32_16x16x32_bf16(qf0, k0, s, 0, 0, 0);
            s = __builtin_amdgcn_mfma_f32_16x16x32_bf16(qf1, k1, s, 0, 0, 0);
            if (need_mask) {
                int col = kt + ni * 16 + lr;
#pragma unroll
                for (int r = 0; r < 4; r++) {
                    int q = qt * 128 + w * 16 + lg * 4 + r;
                    P[ni][r] = (col <= 3840 + q) ? __expf(s[r]) : 0.0f;
                }
            } else {
#pragma unroll
                for (int r = 0; r < 4; r++) P[ni][r] = __expf(s[r]);
            }
        }
        __builtin_amdgcn_s_setprio(0);
#pragma unroll
        for (int ni = 0; ni < 4; ni++)
#pragma unroll
            for (int r = 0; r < 4; r++) {
                int prow = lg * 4 + r;
                Ps[w][prow * 64 + ((ni * 16 + lr) ^ ((prow & 7) << 3))] = f2bf(P[ni][r]);
            }
        __builtin_amdgcn_s_setprio(1);
#pragma unroll
        for (int kk = 0; kk < 2; kk++) {
            int c0 = kk * 32 + lg * 8;
            short8 pf = *(const short8*)&Ps[w][lr * 64 + (c0 ^ ((lr & 7) << 3))];
            lacc = __builtin_amdgcn_mfma_f32_16x16x32_bf16(pf, ones, lacc, 0, 0, 0);
#pragma unroll
            for (int dt = 0; dt < 4; dt++) {
                int vrow = dt * 16 + lr;
                short8 vf = *(const short8*)&Vt[vrow * 64 + (c0 ^ ((vrow & 7) << 3))];
                octx[dt] = __builtin_amdgcn_mfma_f32_16x16x32_bf16(pf, vf, octx[dt], 0, 0, 0);
            }
        }
        __builtin_amdgcn_s_setprio(0);
        __syncthreads();
    }
    size_t obase = (((size_t)(split * 8 + b) * 16 + h) * 256 + qt * 128) * 64;
#pragma unroll
    for (int dt = 0; dt < 4; dt++)
#pragma unroll
        for (int r = 0; r < 4; r++)
            pOct[obase + (size_t)(w * 16 + lg * 4 + r) * 64 + dt * 16 + lr] =
                f2bf(octx[dt][r]);
    if (lr == 0) {
        size_t lbase = ((size_t)(split * 8 + b) * 16 + h) * 256 + qt * 128;
#pragma unroll
        for (int r = 0; r < 4; r++) pL[lbase + w * 16 + lg * 4 + r] = lacc[r];
    }
}

// ---------------- launch ----------------
extern "C" void kernel_launch(void* const* d_in, const int* in_sizes, int n_in,
                              void* d_out, int out_size, void* d_ws, size_t ws_size,
                              hipStream_t stream) {
    (void)in_sizes; (void)n_in; (void)out_size; (void)ws_size;
    const float* x   = (const float*)d_in[0];
    const float* pgt = (const float*)d_in[1];
    const float* Wq  = (const float*)d_in[2];
    const float* bq  = (const float*)d_in[3];
    const float* Wk  = (const float*)d_in[4];
    const float* bk  = (const float*)d_in[5];
    const float* Wv  = (const float*)d_in[6];
    const float* bv  = (const float*)d_in[7];
    const float* Wo  = (const float*)d_in[8];
    const float* bo  = (const float*)d_in[9];
    const float* ln1g = (const float*)d_in[10];
    const float* ln1b = (const float*)d_in[11];
    const float* W1  = (const float*)d_in[12];
    const float* b1  = (const float*)d_in[13];
    const float* W2  = (const float*)d_in[14];
    const float* b2  = (const float*)d_in[15];
    const float* lnfg = (const float*)d_in[16];
    const float* lnfb = (const float*)d_in[17];
    const int* kvidx = (const int*)d_in[20];

    float* out = (float*)d_out;
    float* out_x  = out;
    float* out_lr = out + 2048 * 1024;
    float* out_pt = out + 2 * 2048 * 1024;

    char* ws = (char*)d_ws;
    size_t off = 0;
    auto alloc = [&](size_t bytes) { void* p = ws + off; off += (bytes + 255) & ~(size_t)255; return p; };
    u16* WqkvT = (u16*)alloc((size_t)3072 * 1024 * 2);
    u16* WoT   = (u16*)alloc((size_t)1024 * 1024 * 2);
    u16* W1T   = (u16*)alloc((size_t)4096 * 1024 * 2);
    u16* W2T   = (u16*)alloc((size_t)1024 * 4096 * 2);
    u16* xb    = (u16*)alloc((size_t)2048 * 1024 * 2);
    u16* qbuf  = (u16*)alloc((size_t)2048 * 1024 * 2);
    char* regB = (char*)alloc((size_t)168 * 1024 * 1024);
    // attn phase
    u16* Kbf  = (u16*)regB;
    u16* Vtbf = (u16*)(regB + (size_t)64 * 1024 * 1024);
    u16*   pOct = (u16*)(regB + (size_t)128 * 1024 * 1024);     // 16 MiB bf16
    float* pL   = (float*)(regB + (size_t)162 * 1024 * 1024);
    // FFN phase aliases
    float* p0    = (float*)regB;
    float* xln1f = (float*)(regB + (size_t)16 * 1024 * 1024);
    u16*   xln1b = (u16*)(regB + (size_t)24 * 1024 * 1024);
    u16*   hb    = (u16*)(regB + (size_t)32 * 1024 * 1024);
    float* q0    = (float*)(regB + (size_t)128 * 1024 * 1024);

    prep_wx<<<4096, 256, 0, stream>>>(Wq, Wk, Wv, x, WqkvT, xb);
    mega_prep<<<8064, 256, 0, stream>>>(xb, WqkvT, bq, bk, bv,
                                        out_pt, qbuf, Kbf, Vtbf, pgt, kvidx);
    attn_kernel<<<5632, 512, 0, stream>>>(qbuf, Kbf, Vtbf, pOct, pL,
                                          Wo, W1, W2, WoT, W1T, W2T);
    // WO with fused combine: 256 blocks (split-K x2), raw partials p0/p1
    gemm_wo<<<256, 256, 0, stream>>>(pOct, pL, WoT, p0);
    ln_wo<<<2048, 256, 0, stream>>>(p0, p0 + (size_t)2048 * 1024, bo, x,
                                    ln1g, ln1b, xln1f, xln1b);
    gemm_nt<MODE_F1><<<512, 256, 0, stream>>>(xln1b, W1T, 1024, 1024, 4096, 32, 512,
        b1, nullptr, hb, 0);
    gemm_nt<MODE_F2><<<512, 256, 0, stream>>>(hb, W2T, 4096, 1024, 1024, 8, 128,
        nullptr, q0, nullptr, (size_t)2048 * 1024);
    ln_f2<<<2048, 256, 0, stream>>>(q0, b2, xln1f, lnfg, lnfb, out_lr, out_x);
}

// Round 17
// 323.248 us; speedup vs baseline: 1.1405x; 1.1405x over previous
//
#include <hip/hip_runtime.h>
#include <hip/hip_bf16.h>

typedef unsigned short u16;
typedef __attribute__((ext_vector_type(4))) float f32x4;
typedef __attribute__((ext_vector_type(8))) short short8;

// B=8 QLEN=256 D=1024 H=16 HD=64 FFN=4096 PAGE=16 KV_TOTAL=4096 P=256
// PREFIX=3840 SCALE=0.125
#define MODE_QKV 0
#define MODE_WO  1
#define MODE_F1  2
#define MODE_F2  3

__device__ inline u16 f2bf(float f) {
    __hip_bfloat16 h = __float2bfloat16(f);
    return *(u16*)&h;
}
__device__ inline float bf2f(u16 u) {
    union { unsigned int i; float f; } x; x.i = ((unsigned int)u) << 16; return x.f;
}

typedef __attribute__((address_space(3))) unsigned int lds_u32_t;
typedef const __attribute__((address_space(1))) unsigned int glb_u32_t;
__device__ inline void gload16(const u16* g, u16* l) {
    __builtin_amdgcn_global_load_lds((glb_u32_t*)(const void*)g,
                                     (lds_u32_t*)(void*)l, 16, 0, 0);
}

// ---------------- prep: Wq/Wk/Wv transposes + x cast ----------------
__global__ __launch_bounds__(256) void prep_wx(
    const float* __restrict__ Wq, const float* __restrict__ Wk,
    const float* __restrict__ Wv, const float* __restrict__ x,
    u16* __restrict__ WqkvT, u16* __restrict__ xb) {
    int bid = blockIdx.x;
    int tid = threadIdx.x;
    int tx = tid & 31, ty = tid >> 5;
    if (bid >= 3072) {
        int i = (bid - 3072) * 256 + tid;
        const float4* p = (const float4*)(x + (size_t)i * 8);
        float4 a = p[0], b = p[1];
        u16 t[8] = {f2bf(a.x), f2bf(a.y), f2bf(a.z), f2bf(a.w),
                    f2bf(b.x), f2bf(b.y), f2bf(b.z), f2bf(b.w)};
        *(uint4*)(xb + (size_t)i * 8) = *(const uint4*)t;
        return;
    }
    int m = bid >> 10, r = bid & 1023;
    const float* src = (m == 0) ? Wq : (m == 1) ? Wk : Wv;
    u16* dst = WqkvT + (size_t)m * 1024 * 1024;
    __shared__ float t[32][33];
    int n0 = (r & 31) * 32, k0 = (r >> 5) * 32;
#pragma unroll
    for (int j = 0; j < 32; j += 8)
        t[ty + j][tx] = src[(size_t)(k0 + ty + j) * 1024 + n0 + tx];
    __syncthreads();
#pragma unroll
    for (int j = 0; j < 32; j += 8)
        dst[(size_t)(n0 + ty + j) * 1024 + k0 + tx] = f2bf(t[tx][ty + j]);
}

// ---------------- LN after WO: t = p0+p1+bo+resid; LN -> xln1f, xln1b ------------
__global__ __launch_bounds__(256) void ln_wo(const float* __restrict__ p0,
                                             const float* __restrict__ p1,
                                             const float* __restrict__ bo,
                                             const float* __restrict__ resid,
                                             const float* __restrict__ g,
                                             const float* __restrict__ be,
                                             float* __restrict__ outf,
                                             u16* __restrict__ outb) {
    int row = blockIdx.x;
    int tid = threadIdx.x;
    int c = tid * 4;
    size_t o = (size_t)row * 1024 + c;
    f32x4 v = *(const f32x4*)(p0 + o) + *(const f32x4*)(p1 + o)
            + *(const f32x4*)(bo + c) + *(const f32x4*)(resid + o);
    float s = v[0] + v[1] + v[2] + v[3];
#pragma unroll
    for (int m = 1; m < 64; m <<= 1) s += __shfl_xor(s, m, 64);
    __shared__ float red1[4], red2[4];
    int w = tid >> 6;
    if ((tid & 63) == 0) red1[w] = s;
    __syncthreads();
    float mu = (red1[0] + red1[1] + red1[2] + red1[3]) * (1.0f / 1024.0f);
    f32x4 d = v - mu;
    float q = d[0] * d[0] + d[1] * d[1] + d[2] * d[2] + d[3] * d[3];
#pragma unroll
    for (int m = 1; m < 64; m <<= 1) q += __shfl_xor(q, m, 64);
    if ((tid & 63) == 0) red2[w] = q;
    __syncthreads();
    float var = (red2[0] + red2[1] + red2[2] + red2[3]) * (1.0f / 1024.0f);
    float rs = rsqrtf(var + 1e-5f);
    f32x4 gg = *(const f32x4*)(g + c), bb = *(const f32x4*)(be + c);
    f32x4 ov = d * rs * gg + bb;
    *(f32x4*)(outf + o) = ov;
    u16 t[4] = {f2bf(ov[0]), f2bf(ov[1]), f2bf(ov[2]), f2bf(ov[3])};
    *(uint2*)&outb[o] = *(const uint2*)t;
}

// ------- final LN: lr = q0+q1+q2+q3+b2 -> out_lr; LN(lr + xln1f) -> out_x --------
__global__ __launch_bounds__(256) void ln_f2(const float* __restrict__ q0,
                                             const float* __restrict__ b2,
                                             const float* __restrict__ xln1f,
                                             const float* __restrict__ g,
                                             const float* __restrict__ be,
                                             float* __restrict__ out_lr,
                                             float* __restrict__ out_x) {
    int row = blockIdx.x;
    int tid = threadIdx.x;
    int c = tid * 4;
    size_t o = (size_t)row * 1024 + c;
    const size_t st = (size_t)2048 * 1024;
    f32x4 v = *(const f32x4*)(q0 + o) + *(const f32x4*)(q0 + st + o)
            + *(const f32x4*)(q0 + 2 * st + o) + *(const f32x4*)(q0 + 3 * st + o)
            + *(const f32x4*)(b2 + c);
    *(f32x4*)(out_lr + o) = v;
    v = v + *(const f32x4*)(xln1f + o);
    float s = v[0] + v[1] + v[2] + v[3];
#pragma unroll
    for (int m = 1; m < 64; m <<= 1) s += __shfl_xor(s, m, 64);
    __shared__ float red1[4], red2[4];
    int w = tid >> 6;
    if ((tid & 63) == 0) red1[w] = s;
    __syncthreads();
    float mu = (red1[0] + red1[1] + red1[2] + red1[3]) * (1.0f / 1024.0f);
    f32x4 d = v - mu;
    float q = d[0] * d[0] + d[1] * d[1] + d[2] * d[2] + d[3] * d[3];
#pragma unroll
    for (int m = 1; m < 64; m <<= 1) q += __shfl_xor(q, m, 64);
    if ((tid & 63) == 0) red2[w] = q;
    __syncthreads();
    float var = (red2[0] + red2[1] + red2[2] + red2[3]) * (1.0f / 1024.0f);
    float rs = rsqrtf(var + 1e-5f);
    f32x4 gg = *(const f32x4*)(g + c), bb = *(const f32x4*)(be + c);
    *(f32x4*)(out_x + o) = d * rs * gg + bb;
}

// ---------------- GEMM body: tile 128x128, BK=64, row stride lda ----------------
template <int MODE>
__device__ __forceinline__ void gemm_body(
    u16* As, u16* Bs, int m0, int n0,
    const u16* __restrict__ A, const u16* __restrict__ Bt, int lda, int Kspan, int N,
    const float* __restrict__ bias0, const float* __restrict__ bias1,
    const float* __restrict__ bias2,
    float* __restrict__ o0, u16* __restrict__ ob,
    u16* __restrict__ kbf, u16* __restrict__ vbf, const int* __restrict__ kvidx) {
    int tid = threadIdx.x;
    int l = tid & 63, w = tid >> 6;
    int wr = w >> 1, wc = w & 1;
    int lr = l & 15, lg = l >> 4;
    int lrow8 = l >> 3;
    int scol = ((l & 7) ^ lrow8) << 3;
    f32x4 acc[4][4] = {};
    for (int kb = 0; kb < Kspan; kb += 64) {
#pragma unroll
        for (int p = 0; p < 4; ++p) {
            int chunk = p * 4 + w;
            int r = chunk * 8 + lrow8;
            gload16(&A[(size_t)(m0 + r) * lda + kb + scol], &As[chunk * 512]);
            gload16(&Bt[(size_t)(n0 + r) * lda + kb + scol], &Bs[chunk * 512]);
        }
        __syncthreads();
#pragma unroll
        for (int kk = 0; kk < 2; ++kk) {
            short8 a[4], b[4];
            int c0 = kk * 32 + lg * 8;
#pragma unroll
            for (int mi = 0; mi < 4; mi++) {
                int row = wr * 64 + mi * 16 + lr;
                a[mi] = *(const short8*)&As[row * 64 + (c0 ^ ((row & 7) << 3))];
            }
#pragma unroll
            for (int ni = 0; ni < 4; ni++) {
                int row = wc * 64 + ni * 16 + lr;
                b[ni] = *(const short8*)&Bs[row * 64 + (c0 ^ ((row & 7) << 3))];
            }
#pragma unroll
            for (int mi = 0; mi < 4; mi++)
#pragma unroll
                for (int ni = 0; ni < 4; ni++)
                    acc[mi][ni] = __builtin_amdgcn_mfma_f32_16x16x32_bf16(
                        a[mi], b[ni], acc[mi][ni], 0, 0, 0);
        }
        __syncthreads();
    }
#pragma unroll
    for (int mi = 0; mi < 4; mi++) {
#pragma unroll
        for (int ni = 0; ni < 4; ni++) {
#pragma unroll
            for (int r = 0; r < 4; r++) {
                int row = m0 + wr * 64 + mi * 16 + lg * 4 + r;
                int col = n0 + wc * 64 + ni * 16 + lr;
                float v = acc[mi][ni][r];
                if constexpr (MODE == MODE_QKV) {
                    int sel = col >> 10, c = col & 1023;
                    int b = row >> 8, ii = row & 255;
                    int h = (c >> 6), hd = c & 63;
                    if (sel == 0) {
                        ob[(size_t)row * 1024 + c] = f2bf((v + bias0[c]) * 0.125f);
                    } else if (sel == 1) {
                        float val = v + bias1[c];
                        int page = kvidx[b * 256 + 240 + (ii >> 4)];
                        o0[(size_t)page * 32768 + (size_t)(ii & 15) * 1024 + c] = val;
                        kbf[((size_t)(b * 16 + h) * 4096 + 3840 + ii) * 64 + hd] = f2bf(val);
                    } else {
                        float val = v + bias2[c];
                        int page = kvidx[b * 256 + 240 + (ii >> 4)];
                        o0[(size_t)page * 32768 + 16384 + (size_t)(ii & 15) * 1024 + c] = val;
                        vbf[((size_t)(b * 16 + h) * 64 + hd) * 4096 + 3840 + ii] = f2bf(val);
                    }
                } else if constexpr (MODE == MODE_F1) {
                    float t = v + bias0[col];
                    ob[(size_t)row * N + col] = f2bf(fmaxf(t, 0.0f));
                } else { // raw split-K partial
                    o0[(size_t)row * N + col] = v;
                }
            }
        }
    }
}

// split-K wrapper
template <int MODE>
__global__ __launch_bounds__(256) void gemm_nt(
    const u16* __restrict__ A, const u16* __restrict__ Bt,
    int lda, int Kspan, int N, int gx, int nper,
    const float* __restrict__ bias0,
    float* __restrict__ o0, u16* __restrict__ ob, size_t osplit) {
    __shared__ __align__(16) u16 smem[128 * 64 * 2];
    int bid = blockIdx.x;
    int split = bid / nper, t = bid % nper;
    gemm_body<MODE>(smem, smem + 128 * 64, (t / gx) * 128, (t % gx) * 128,
                    A + (size_t)split * Kspan, Bt + (size_t)split * Kspan,
                    lda, Kspan, N, bias0, nullptr, nullptr,
                    o0 ? o0 + (size_t)split * osplit : nullptr, ob,
                    nullptr, nullptr, nullptr);
}

// ---- mega v4: 8064 blocks. bid%21==20 -> QKV GEMM (384); else single-read prefix.
// ---- f32 copy uses non-temporal stores (output-only, never re-read).
__global__ __launch_bounds__(256) void mega_prep(
    const u16* __restrict__ xb, const u16* __restrict__ WqkvT,
    const float* __restrict__ bq, const float* __restrict__ bk,
    const float* __restrict__ bv,
    float* __restrict__ out_pt, u16* __restrict__ qbuf,
    u16* __restrict__ Kbf, u16* __restrict__ Vtbf,
    const float* __restrict__ pgt, const int* __restrict__ kvidx) {
    __shared__ __align__(16) u16 smem[128 * 64 * 2];
    int bid = blockIdx.x;
    int tid = threadIdx.x;
    if (bid % 21 == 20) {
        int t = bid / 21;
        gemm_body<MODE_QKV>(smem, smem + 8192, (t / 24) * 128, (t % 24) * 128,
                            xb, WqkvT, 1024, 1024, 3072, bq, bk, bv,
                            out_pt, qbuf, Kbf, Vtbf, kvidx);
        return;
    }
    int idx = (bid / 21) * 20 + (bid % 21);   // 0..7679
    int tile = idx % 60, rest = idx / 60;
    int h = rest & 15, b = rest >> 4;
    int T0 = tile * 64;
    int rr = tid >> 4;
    int hdq = tid & 15;
    u16* vt = smem;      // [64][68]
    size_t kdst_base = ((size_t)(b * 16 + h) * 4096 + T0) * 64;
#pragma unroll
    for (int p = 0; p < 4; ++p) {
        int i = p * 16 + rr;
        int page = kvidx[b * 256 + (T0 >> 4) + p];
        size_t src = (size_t)page * 32768 + (size_t)rr * 1024 + h * 64 + hdq * 4;
        f32x4 kf = *(const f32x4*)(pgt + src);
        __builtin_nontemporal_store(kf, (f32x4*)(out_pt + src));
        u16 kb4[4] = {f2bf(kf[0]), f2bf(kf[1]), f2bf(kf[2]), f2bf(kf[3])};
        *(uint2*)&Kbf[kdst_base + (size_t)i * 64 + hdq * 4] = *(const uint2*)kb4;
        f32x4 vf = *(const f32x4*)(pgt + src + 16384);
        __builtin_nontemporal_store(vf, (f32x4*)(out_pt + src + 16384));
        u16 vb4[4] = {f2bf(vf[0]), f2bf(vf[1]), f2bf(vf[2]), f2bf(vf[3])};
        *(uint2*)&vt[i * 68 + hdq * 4] = *(const uint2*)vb4;
    }
    __syncthreads();
    size_t vdst_base = (size_t)(b * 16 + h) * 64 * 4096 + T0;
#pragma unroll
    for (int p = 0; p < 4; ++p) {
        int hd = p * 16 + rr;
        u16 o[4];
#pragma unroll
        for (int j = 0; j < 4; ++j) o[j] = vt[(hdq * 4 + j) * 68 + hd];
        *(uint2*)&Vtbf[vdst_base + (size_t)hd * 4096 + hdq * 4] = *(const uint2*)o;
    }
}

// ---- attention (1024 blocks) + Wo/W1/W2 transposes (4608 blocks x 2 tiles) ----
__global__ __launch_bounds__(512) void attn_kernel(const u16* __restrict__ qb,
                                                   const u16* __restrict__ Kbf,
                                                   const u16* __restrict__ Vtbf,
                                                   u16* __restrict__ pOct,
                                                   float* __restrict__ pL,
                                                   const float* __restrict__ Wo,
                                                   const float* __restrict__ W1,
                                                   const float* __restrict__ W2,
                                                   u16* __restrict__ WoT,
                                                   u16* __restrict__ W1T,
                                                   u16* __restrict__ W2T) {
    __shared__ u16 Ks[64 * 64];
    __shared__ u16 Vt[64 * 64];
    __shared__ u16 Ps[8][16 * 64];
    int bid = blockIdx.x;
    int tid = threadIdx.x;
    if (bid >= 1024) {
        int sub = tid >> 8, t2 = tid & 255;
        int wb = (bid - 1024) * 2 + sub;   // 0..9215
        const float* src; u16* dst; int K, N, bx, by;
        if (wb < 1024) {
            bx = wb & 31; by = wb >> 5; K = 1024; N = 1024; src = Wo; dst = WoT;
        } else if (wb < 5120) {
            int r = wb - 1024; bx = r & 127; by = r >> 7; K = 1024; N = 4096; src = W1; dst = W1T;
        } else {
            int r = wb - 5120; bx = r & 31; by = r >> 5; K = 4096; N = 1024; src = W2; dst = W2T;
        }
        float* t = sub ? (float*)Vt : (float*)Ks;
        int tx = t2 & 31, ty = t2 >> 5;
        int n0 = bx * 32, k0 = by * 32;
#pragma unroll
        for (int jj = 0; jj < 32; jj += 8)
            t[(ty + jj) * 33 + tx] = src[(size_t)(k0 + ty + jj) * N + n0 + tx];
        __syncthreads();
#pragma unroll
        for (int jj = 0; jj < 32; jj += 8)
            dst[(size_t)(n0 + ty + jj) * K + k0 + tx] = f2bf(t[tx * 33 + ty + jj]);
        return;
    }
    int l = tid & 63, w = tid >> 6;
    int lr = l & 15, lg = l >> 4;
    int x = bid & 7, qt = x >> 2, split = x & 3;
    int h = (bid >> 3) & 15, b = bid >> 7;

    int qrow = qt * 128 + w * 16 + lr;
    const u16* qptr = qb + (size_t)(b * 256 + qrow) * 1024 + h * 64 + lg * 8;
    short8 qf0 = *(const short8*)qptr;
    short8 qf1 = *(const short8*)(qptr + 32);

    const u16* kslab = Kbf + (size_t)(b * 16 + h) * 4096 * 64;
    const u16* vslab = Vtbf + (size_t)(b * 16 + h) * 64 * 4096;

    f32x4 octx[4] = {};
    f32x4 lacc = {};
    short8 ones;
#pragma unroll
    for (int jj = 0; jj < 8; jj++) ones[jj] = (short)0x3F80;

    int qbase = 3840 + qt * 128;
    int ntiles = (qbase + 128) >> 6;
    int tstart = split * 16;
    int tend = min(tstart + 16, ntiles);
    int kt0 = tstart * 64, kt1 = tend * 64;

    int srow = tid >> 3, scol8 = (tid & 7) * 8;
    int sdst = srow * 64 + (scol8 ^ ((srow & 7) << 3));
    const u16* kp = kslab + srow * 64 + scol8;
    const u16* vp = vslab + (size_t)srow * 4096 + scol8;

    uint4 kreg = *(const uint4*)(kp + (size_t)kt0 * 64);
    uint4 vreg = *(const uint4*)(vp + kt0);
    for (int kt = kt0; kt < kt1; kt += 64) {
        *(uint4*)&Ks[sdst] = kreg;
        *(uint4*)&Vt[sdst] = vreg;
        __syncthreads();
        bool hn = (kt + 64) < kt1;
        if (hn) {
            kreg = *(const uint4*)(kp + (size_t)(kt + 64) * 64);
            vreg = *(const uint4*)(vp + kt + 64);
        }
        float P[4][4];
        bool need_mask = (kt + 63 > qbase);
        __builtin_amdgcn_s_setprio(1);
#pragma unroll
        for (int ni = 0; ni < 4; ni++) {
            f32x4 s = {};
            int krow = ni * 16 + lr;
            int swz = (krow & 7) << 3;
            short8 k0 = *(const short8*)&Ks[krow * 64 + ((lg * 8) ^ swz)];
            short8 k1 = *(const short8*)&Ks[krow * 64 + ((32 + lg * 8) ^ swz)];
            s = __builtin_amdgcn_mfma_f32_16x16x32_bf16(qf0, k0, s, 0, 0, 0);
            s = __builtin_amdgcn_mfma_f32_16x16x32_bf16(qf1, k1, s, 0, 0, 0);
            if (need_mask) {
                int col = kt + ni * 16 + lr;
#pragma unroll
                for (int r = 0; r < 4; r++) {
                    int q = qt * 128 + w * 16 + lg * 4 + r;
                    P[ni][r] = (col <= 3840 + q) ? __expf(s[r]) : 0.0f;
                }
            } else {
#pragma unroll
                for (int r = 0; r < 4; r++) P[ni][r] = __expf(s[r]);
            }
        }
        __builtin_amdgcn_s_setprio(0);
#pragma unroll
        for (int ni = 0; ni < 4; ni++)
#pragma unroll
            for (int r = 0; r < 4; r++) {
                int prow = lg * 4 + r;
                Ps[w][prow * 64 + ((ni * 16 + lr) ^ ((prow & 7) << 3))] = f2bf(P[ni][r]);
            }
        __builtin_amdgcn_s_setprio(1);
#pragma unroll
        for (int kk = 0; kk < 2; kk++) {
            int c0 = kk * 32 + lg * 8;
            short8 pf = *(const short8*)&Ps[w][lr * 64 + (c0 ^ ((lr & 7) << 3))];
            lacc = __builtin_amdgcn_mfma_f32_16x16x32_bf16(pf, ones, lacc, 0, 0, 0);
#pragma unroll
            for (int dt = 0; dt < 4; dt++) {
                int vrow = dt * 16 + lr;
                short8 vf = *(const short8*)&Vt[vrow * 64 + (c0 ^ ((vrow & 7) << 3))];
                octx[dt] = __builtin_amdgcn_mfma_f32_16x16x32_bf16(pf, vf, octx[dt], 0, 0, 0);
            }
        }
        __builtin_amdgcn_s_setprio(0);
        __syncthreads();
    }
    size_t obase = (((size_t)(split * 8 + b) * 16 + h) * 256 + qt * 128) * 64;
#pragma unroll
    for (int dt = 0; dt < 4; dt++)
#pragma unroll
        for (int r = 0; r < 4; r++)
            pOct[obase + (size_t)(w * 16 + lg * 4 + r) * 64 + dt * 16 + lr] =
                f2bf(octx[dt][r]);
    if (lr == 0) {
        size_t lbase = ((size_t)(split * 8 + b) * 16 + h) * 256 + qt * 128;
#pragma unroll
        for (int r = 0; r < 4; r++) pL[lbase + w * 16 + lg * 4 + r] = lacc[r];
    }
}

// ---------------- combine bf16 partials -> ctx bf16 ----------------
__global__ __launch_bounds__(256) void attn_combine(const u16* __restrict__ pOct,
                                                    const float* __restrict__ pL,
                                                    u16* __restrict__ ctxb) {
    int row = blockIdx.x;
    int b = row >> 8, q = row & 255;
    int tid = threadIdx.x;
    int h = tid >> 4, dq = (tid & 15) * 4;
    size_t stride = (size_t)128 * 256 * 64;
    size_t base = ((size_t)(b * 16 + h) * 256 + q) * 64 + dq;
    size_t lstride = 128 * 256;
    size_t lbase = (size_t)(b * 16 + h) * 256 + q;
    f32x4 s = {};
    float ls = 0.0f;
#pragma unroll
    for (int sp = 0; sp < 4; sp++) {
        u16 a[4];
        *(uint2*)a = *(const uint2*)&pOct[sp * stride + base];
#pragma unroll
        for (int j = 0; j < 4; j++) s[j] += bf2f(a[j]);
        ls += pL[sp * lstride + lbase];
    }
    float inv = 1.0f / ls;
    u16 o[4] = {f2bf(s[0] * inv), f2bf(s[1] * inv), f2bf(s[2] * inv), f2bf(s[3] * inv)};
    *(uint2*)&ctxb[(size_t)row * 1024 + h * 64 + dq] = *(const uint2*)o;
}

// ---------------- launch ----------------
extern "C" void kernel_launch(void* const* d_in, const int* in_sizes, int n_in,
                              void* d_out, int out_size, void* d_ws, size_t ws_size,
                              hipStream_t stream) {
    (void)in_sizes; (void)n_in; (void)out_size; (void)ws_size;
    const float* x   = (const float*)d_in[0];
    const float* pgt = (const float*)d_in[1];
    const float* Wq  = (const float*)d_in[2];
    const float* bq  = (const float*)d_in[3];
    const float* Wk  = (const float*)d_in[4];
    const float* bk  = (const float*)d_in[5];
    const float* Wv  = (const float*)d_in[6];
    const float* bv  = (const float*)d_in[7];
    const float* Wo  = (const float*)d_in[8];
    const float* bo  = (const float*)d_in[9];
    const float* ln1g = (const float*)d_in[10];
    const float* ln1b = (const float*)d_in[11];
    const float* W1  = (const float*)d_in[12];
    const float* b1  = (const float*)d_in[13];
    const float* W2  = (const float*)d_in[14];
    const float* b2  = (const float*)d_in[15];
    const float* lnfg = (const float*)d_in[16];
    const float* lnfb = (const float*)d_in[17];
    const int* kvidx = (const int*)d_in[20];

    float* out = (float*)d_out;
    float* out_x  = out;
    float* out_lr = out + 2048 * 1024;
    float* out_pt = out + 2 * 2048 * 1024;

    char* ws = (char*)d_ws;
    size_t off = 0;
    auto alloc = [&](size_t bytes) { void* p = ws + off; off += (bytes + 255) & ~(size_t)255; return p; };
    u16* WqkvT = (u16*)alloc((size_t)3072 * 1024 * 2);
    u16* WoT   = (u16*)alloc((size_t)1024 * 1024 * 2);
    u16* W1T   = (u16*)alloc((size_t)4096 * 1024 * 2);
    u16* W2T   = (u16*)alloc((size_t)1024 * 4096 * 2);
    u16* xb    = (u16*)alloc((size_t)2048 * 1024 * 2);
    u16* qbuf  = (u16*)alloc((size_t)2048 * 1024 * 2);
    u16* ctxb  = (u16*)alloc((size_t)2048 * 1024 * 2);
    char* regB = (char*)alloc((size_t)168 * 1024 * 1024);
    // attn phase
    u16* Kbf  = (u16*)regB;
    u16* Vtbf = (u16*)(regB + (size_t)64 * 1024 * 1024);
    u16*   pOct = (u16*)(regB + (size_t)128 * 1024 * 1024);     // 16 MiB bf16
    float* pL   = (float*)(regB + (size_t)162 * 1024 * 1024);
    // FFN phase aliases
    float* p0    = (float*)regB;
    float* xln1f = (float*)(regB + (size_t)16 * 1024 * 1024);
    u16*   xln1b = (u16*)(regB + (size_t)24 * 1024 * 1024);
    u16*   hb    = (u16*)(regB + (size_t)32 * 1024 * 1024);
    float* q0    = (float*)(regB + (size_t)128 * 1024 * 1024);

    prep_wx<<<4096, 256, 0, stream>>>(Wq, Wk, Wv, x, WqkvT, xb);
    mega_prep<<<8064, 256, 0, stream>>>(xb, WqkvT, bq, bk, bv,
                                        out_pt, qbuf, Kbf, Vtbf, pgt, kvidx);
    attn_kernel<<<5632, 512, 0, stream>>>(qbuf, Kbf, Vtbf, pOct, pL,
                                          Wo, W1, W2, WoT, W1T, W2T);
    attn_combine<<<2048, 256, 0, stream>>>(pOct, pL, ctxb);
    gemm_nt<MODE_WO><<<256, 256, 0, stream>>>(ctxb, WoT, 1024, 512, 1024, 8, 128,
        nullptr, p0, nullptr, (size_t)2048 * 1024);
    ln_wo<<<2048, 256, 0, stream>>>(p0, p0 + (size_t)2048 * 1024, bo, x,
                                    ln1g, ln1b, xln1f, xln1b);
    gemm_nt<MODE_F1><<<512, 256, 0, stream>>>(xln1b, W1T, 1024, 1024, 4096, 32, 512,
        b1, nullptr, hb, 0);
    gemm_nt<MODE_F2><<<512, 256, 0, stream>>>(hb, W2T, 4096, 1024, 1024, 8, 128,
        nullptr, q0, nullptr, (size_t)2048 * 1024);
    ln_f2<<<2048, 256, 0, stream>>>(q0, b2, xln1f, lnfg, lnfb, out_lr, out_x);
}